// Round 3
// baseline (1926.975 us; speedup 1.0000x reference)
//
#include <hip/hip_runtime.h>

// ---------------------------------------------------------------------------
// TimeSeriesTransformer fused single-kernel pipeline (persistent 512 blocks,
// manual device-scope grid barriers). Phases:
//  P0 prep wT | P1 proj q,k,vT | P2 attn -> r | P3 gemm W1 | P4 reduce+sig h1
//  P5 gemm W2 | P6 reduce+sig h2 | P7 gemm W3 | P8 reduce+bias -> out
// 512 blocks x 256 thr, __launch_bounds__(256,2) => 2 blocks/CU co-resident.
// ---------------------------------------------------------------------------

#define DI __device__ __forceinline__

typedef __attribute__((ext_vector_type(4))) float f32x4;
typedef __attribute__((ext_vector_type(2))) float f32x2;
typedef __attribute__((ext_vector_type(8))) short bf16x8;

DI unsigned short f2bf(float f) {      // fp32 -> bf16, round-to-nearest-even
  unsigned int u = __float_as_uint(f);
  u += 0x7fffu + ((u >> 16) & 1u);
  return (unsigned short)(u >> 16);
}

union SMem {                           // phase-exclusive LDS overlays
  unsigned short vtile[64 * 128];      // P1: v transpose staging (16 KB)
  unsigned short p[4][16 * 264];       // P2: P tiles, padded (33.8 KB)
};

DI void gridbar(unsigned* ctr, unsigned target) {
  __threadfence();                     // drain this thread's writes to device
  __syncthreads();                     // all threads in block fenced
  if (threadIdx.x == 0) {
    __hip_atomic_fetch_add(ctr, 1u, __ATOMIC_RELEASE, __HIP_MEMORY_SCOPE_AGENT);
    while (__hip_atomic_load(ctr, __ATOMIC_ACQUIRE, __HIP_MEMORY_SCOPE_AGENT) < target)
      __builtin_amdgcn_s_sleep(8);
  }
  __syncthreads();
  __threadfence();                     // acquire: invalidate stale L1 lines
}

// K-split GEMM phase: A bf16 [128 x lda], B fp32 [K x ldb]; wave owns 32 N-cols
// x 128 M-rows; B loaded straight to fragment regs; 2-set register pipeline.
DI void gemm_phase(const unsigned short* __restrict__ A, int lda,
                   const float* __restrict__ B, int ldb,
                   float* __restrict__ slab, int ldo, int nChunks,
                   int bx, int by, int tid) {
  int wv = tid >> 6, lane = tid & 63;
  int quad = lane >> 4, l15 = lane & 15;
  int n0 = bx * 128 + wv * 32;
  size_t k0 = (size_t)by * nChunks * 32;
  const float* bb = B + (k0 + quad * 8) * (size_t)ldb + n0 + l15;
  const unsigned short* ab = A + (size_t)l15 * lda + k0 + quad * 8;

  f32x4 acc[8][2];
#pragma unroll
  for (int mt = 0; mt < 8; ++mt)
#pragma unroll
    for (int nt = 0; nt < 2; ++nt) acc[mt][nt] = (f32x4){0.f, 0.f, 0.f, 0.f};

  float b0[2][8]; bf16x8 a0[8];
  float b1[2][8]; bf16x8 a1[8];

#define LOADSET(bs, as, c)                                                     \
  {                                                                            \
    const float* bp = bb + (size_t)(c) * 32 * ldb;                             \
    const unsigned short* ap = ab + (size_t)(c) * 32;                          \
    _Pragma("unroll") for (int nt = 0; nt < 2; ++nt)                           \
        _Pragma("unroll") for (int j = 0; j < 8; ++j)                          \
            bs[nt][j] = bp[(size_t)j * ldb + nt * 16];                         \
    _Pragma("unroll") for (int mt = 0; mt < 8; ++mt)                           \
        as[mt] = *(const bf16x8*)(ap + (size_t)mt * 16 * lda);                 \
  }
#define COMPUTE(bs, as)                                                        \
  {                                                                            \
    bf16x8 bF[2];                                                              \
    _Pragma("unroll") for (int nt = 0; nt < 2; ++nt)                           \
        _Pragma("unroll") for (int j = 0; j < 8; ++j)                          \
            bF[nt][j] = (short)f2bf(bs[nt][j]);                                \
    _Pragma("unroll") for (int mt = 0; mt < 8; ++mt)                           \
        _Pragma("unroll") for (int nt = 0; nt < 2; ++nt)                       \
            acc[mt][nt] =                                                      \
                __builtin_amdgcn_mfma_f32_16x16x32_bf16(as[mt], bF[nt],        \
                                                        acc[mt][nt], 0, 0, 0);\
  }

  LOADSET(b0, a0, 0)
  for (int c = 0; c < nChunks; c += 2) {     // nChunks even (32 / 2 / 4)
    LOADSET(b1, a1, c + 1)
    COMPUTE(b0, a0)
    if (c + 2 < nChunks) LOADSET(b0, a0, c + 2)
    COMPUTE(b1, a1)
  }
#undef LOADSET
#undef COMPUTE

  float* out = slab + (size_t)by * (size_t)ldo * 128;
#pragma unroll
  for (int mt = 0; mt < 8; ++mt)
#pragma unroll
    for (int nt = 0; nt < 2; ++nt)
#pragma unroll
      for (int r4 = 0; r4 < 4; ++r4)
        out[(size_t)(mt * 16 + quad * 4 + r4) * ldo + n0 + nt * 16 + l15] =
            acc[mt][nt][r4];
}

template <int NS>
DI void reduce_sig_bf(const float* __restrict__ slabs, int stride,
                      const float* __restrict__ bias, int bmask,
                      unsigned* __restrict__ outp, int gid) {
  int e = gid * 2;
  f32x2 s = {0.f, 0.f};
#pragma unroll
  for (int y = 0; y < NS; ++y) {
    f32x2 v = *(const f32x2*)(slabs + (size_t)y * stride + e);
    s.x += v.x; s.y += v.y;
  }
  f32x2 bv = *(const f32x2*)(bias + (e & bmask));
  s.x += bv.x; s.y += bv.y;
  unsigned pk = (unsigned)f2bf(1.f / (1.f + __expf(-s.x))) |
                ((unsigned)f2bf(1.f / (1.f + __expf(-s.y))) << 16);
  outp[gid] = pk;
}

__global__ __launch_bounds__(256, 2) void fused_kernel(
    const float* __restrict__ X,
    const float* __restrict__ Qw, const float* __restrict__ Qb,
    const float* __restrict__ Kw, const float* __restrict__ Kb,
    const float* __restrict__ Vw, const float* __restrict__ Vb,
    const float* __restrict__ W1, const float* __restrict__ b1,
    const float* __restrict__ W2, const float* __restrict__ b2,
    const float* __restrict__ W3, const float* __restrict__ b3,
    float* __restrict__ outF,
    unsigned short* __restrict__ wT, unsigned short* __restrict__ q_ws,
    unsigned short* __restrict__ k_ws, unsigned short* __restrict__ vT_ws,
    unsigned short* __restrict__ r_ws,
    float* __restrict__ g1, unsigned short* __restrict__ h1bf,
    float* __restrict__ g2, unsigned short* __restrict__ h2bf,
    float* __restrict__ g3, unsigned* __restrict__ ctr) {
  __shared__ SMem sm;
  const int bid = blockIdx.x, tid = threadIdx.x;
  const int wv = tid >> 6, lane = tid & 63;
  const int quad = lane >> 4, l15 = lane & 15;
  unsigned gen = 0;

  // ---- P0: wT[w][no][ni] = bf16(W[w][ni][no]) ------------------------------
  {
    int gid = bid * 256 + tid;
    if (gid < 49152) {
      int w = gid >> 14, j = gid & 16383;
      int no = j >> 7, ni = j & 127;
      const float* src = (w == 0) ? Qw : (w == 1) ? Kw : Vw;
      wT[gid] = f2bf(src[ni * 128 + no]);
    }
  }

  // ---- P1 preamble (no wT dep): X A-fragments ------------------------------
  const int R0blk = bid * 64;
  bf16x8 af[4];
  {
    const float* xbase = X + (size_t)(R0blk + wv * 16 + l15) * 128 + quad * 8;
#pragma unroll
    for (int kc = 0; kc < 4; ++kc) {
      f32x4 x0 = *(const f32x4*)(xbase + kc * 32);
      f32x4 x1 = *(const f32x4*)(xbase + kc * 32 + 4);
      bf16x8 a;
#pragma unroll
      for (int j = 0; j < 4; ++j) { a[j] = (short)f2bf(x0[j]); a[4 + j] = (short)f2bf(x1[j]); }
      af[kc] = a;
    }
  }
  gen += 512; gridbar(ctr, gen);                 // B1: wT ready

  // ---- P1: projections -----------------------------------------------------
#pragma unroll
  for (int p = 0; p < 3; ++p) {
    const unsigned short* wt = wT + p * 16384;
    const float* bias = (p == 0) ? Qb : (p == 1) ? Kb : Vb;
#pragma unroll
    for (int nt = 0; nt < 8; ++nt) {
      f32x4 acc = {0.f, 0.f, 0.f, 0.f};
#pragma unroll
      for (int kc = 0; kc < 4; ++kc) {
        bf16x8 b = *(const bf16x8*)(wt + (size_t)(nt * 16 + l15) * 128 + kc * 32 + quad * 8);
        acc = __builtin_amdgcn_mfma_f32_16x16x32_bf16(af[kc], b, acc, 0, 0, 0);
      }
      int no = nt * 16 + l15;
      float bv = bias[no];
#pragma unroll
      for (int r4 = 0; r4 < 4; ++r4) {          // C/D: col=l15, row=quad*4+r4
        unsigned short val = f2bf(acc[r4] + bv);
        int rowLoc = wv * 16 + quad * 4 + r4;
        int row = R0blk + rowLoc;
        if (p == 0)      q_ws[(size_t)row * 128 + no] = val;
        else if (p == 1) k_ws[(size_t)row * 128 + no] = val;
        else             sm.vtile[rowLoc * 128 + no] = val;
      }
    }
  }
  __syncthreads();
  {  // vT[b][no][t]: 32 shorts/thread as 4 x 16 B stores
    int no = tid >> 1;
    int th = (tid & 1) * 32;
    int bb2 = R0blk >> 8;
    int tBase = (R0blk & 255) + th;
    unsigned short* dst = vT_ws + ((size_t)bb2 * 128 + no) * 256 + tBase;
#pragma unroll
    for (int g = 0; g < 4; ++g) {
      bf16x8 v8;
#pragma unroll
      for (int i = 0; i < 8; ++i) v8[i] = (short)sm.vtile[(th + g * 8 + i) * 128 + no];
      *(bf16x8*)(dst + g * 8) = v8;
    }
  }
  gen += 512; gridbar(ctr, gen);                 // B2: q,k,vT ready

  // ---- P2: attention -> r ---------------------------------------------------
  {
    int b = bid >> 2;
    int t0 = (bid & 3) * 64 + wv * 16;
    bf16x8 kf[4];
    const unsigned short* kbase = k_ws + ((size_t)b * 256 + t0 + l15) * 128 + quad * 8;
#pragma unroll
    for (int kc = 0; kc < 4; ++kc) kf[kc] = *(const bf16x8*)(kbase + kc * 32);

    f32x4 sc[16];
#pragma unroll
    for (int st = 0; st < 16; ++st) {
      f32x4 acc = {0.f, 0.f, 0.f, 0.f};
      const unsigned short* qbase = q_ws + ((size_t)b * 256 + st * 16 + l15) * 128 + quad * 8;
#pragma unroll
      for (int kc = 0; kc < 4; ++kc) {
        bf16x8 qf = *(const bf16x8*)(qbase + kc * 32);
        acc = __builtin_amdgcn_mfma_f32_16x16x32_bf16(kf[kc], qf, acc, 0, 0, 0);
      }
      sc[st] = acc;
    }

    float inv[4];
#pragma unroll
    for (int r4 = 0; r4 < 4; ++r4) {
      float m = sc[0][r4];
#pragma unroll
      for (int st = 1; st < 16; ++st) m = fmaxf(m, sc[st][r4]);
#pragma unroll
      for (int d = 1; d < 16; d <<= 1) m = fmaxf(m, __shfl_xor(m, d, 64));
      float s = 0.f;
#pragma unroll
      for (int st = 0; st < 16; ++st) { float e = __expf(sc[st][r4] - m); sc[st][r4] = e; s += e; }
#pragma unroll
      for (int d = 1; d < 16; d <<= 1) s += __shfl_xor(s, d, 64);
      inv[r4] = 1.f / s;
    }

#pragma unroll
    for (int st = 0; st < 16; ++st)
#pragma unroll
      for (int r4 = 0; r4 < 4; ++r4)
        sm.p[wv][(quad * 4 + r4) * 264 + st * 16 + l15] = f2bf(sc[st][r4] * inv[r4]);
    __syncthreads();

    const unsigned short* pbase = &sm.p[wv][l15 * 264 + quad * 8];
#pragma unroll
    for (int vt = 0; vt < 8; ++vt) {
      f32x4 acc = {0.f, 0.f, 0.f, 0.f};
      const unsigned short* vbase = vT_ws + ((size_t)b * 128 + vt * 16 + l15) * 256 + quad * 8;
#pragma unroll
      for (int s8 = 0; s8 < 8; ++s8) {
        bf16x8 pf = *(const bf16x8*)(pbase + s8 * 32);
        bf16x8 vf = *(const bf16x8*)(vbase + s8 * 32);
        acc = __builtin_amdgcn_mfma_f32_16x16x32_bf16(pf, vf, acc, 0, 0, 0);
      }
#pragma unroll
      for (int r4 = 0; r4 < 4; ++r4)
        r_ws[((size_t)b * 256 + t0 + quad * 4 + r4) * 128 + vt * 16 + l15] = f2bf(acc[r4]);
    }
  }
  gen += 512; gridbar(ctr, gen);                 // B3: r ready

  // ---- P3: h1pre = r @ W1 (K=32768, 32-way split) --------------------------
  gemm_phase(r_ws, 32768, W1, 2048, g1, 2048, 32, bid & 15, bid >> 4, tid);
  gen += 512; gridbar(ctr, gen);                 // B4

  // ---- P4: h1 = sigmoid(reduce(g1) + b1) -----------------------------------
  reduce_sig_bf<32>(g1, 262144, b1, 2047, (unsigned*)h1bf, bid * 256 + tid);
  gen += 512; gridbar(ctr, gen);                 // B5

  // ---- P5: h2pre = h1 @ W2 (K=2048, 32-way split) --------------------------
  gemm_phase(h1bf, 2048, W2, 2048, g2, 2048, 2, bid & 15, bid >> 4, tid);
  gen += 512; gridbar(ctr, gen);                 // B6

  // ---- P6: h2 = sigmoid(reduce(g2) + b2) -----------------------------------
  reduce_sig_bf<32>(g2, 262144, b2, 2047, (unsigned*)h2bf, bid * 256 + tid);
  gen += 512; gridbar(ctr, gen);                 // B7

  // ---- P7: outpre = h2 @ W3 (K=2048, 16-way split, N=4096) -----------------
  gemm_phase(h2bf, 2048, W3, 4096, g3, 4096, 4, bid & 31, bid >> 5, tid);
  gen += 512; gridbar(ctr, gen);                 // B8

  // ---- P8: out = reduce(g3) + b3 -------------------------------------------
  {
    int e = (bid * 256 + tid) * 4;
    f32x4 s = {0.f, 0.f, 0.f, 0.f};
#pragma unroll
    for (int y = 0; y < 16; ++y) {
      f32x4 v = *(const f32x4*)(g3 + (size_t)y * 524288 + e);
      s.x += v.x; s.y += v.y; s.z += v.z; s.w += v.w;
    }
    f32x4 bv = *(const f32x4*)(b3 + (e & 4095));
    s.x += bv.x; s.y += bv.y; s.z += bv.z; s.w += bv.w;
    *(f32x4*)(outF + e) = s;
  }
}

// ---------------------------------------------------------------------------
extern "C" void kernel_launch(void* const* d_in, const int* in_sizes, int n_in,
                              void* d_out, int out_size, void* d_ws, size_t ws_size,
                              hipStream_t stream) {
  const float* X  = (const float*)d_in[0];
  const float* Qw = (const float*)d_in[1];
  const float* Qb = (const float*)d_in[2];
  const float* Kw = (const float*)d_in[3];
  const float* Kb = (const float*)d_in[4];
  const float* Vw = (const float*)d_in[5];
  const float* Vb = (const float*)d_in[6];
  const float* W1 = (const float*)d_in[7];
  const float* b1 = (const float*)d_in[8];
  const float* W2 = (const float*)d_in[9];
  const float* b2 = (const float*)d_in[10];
  const float* W3 = (const float*)d_in[11];
  const float* b3 = (const float*)d_in[12];

  char* ws = (char*)d_ws;
  unsigned short* wT    = (unsigned short*)(ws + 0);          //  96 KB
  unsigned short* q_ws  = (unsigned short*)(ws + 98304);      // 8.39 MB
  unsigned short* k_ws  = (unsigned short*)(ws + 8486912);    // 8.39 MB
  unsigned short* vT_ws = (unsigned short*)(ws + 16875520);   // 8.39 MB
  unsigned short* r_ws  = (unsigned short*)(ws + 25264128);   // 8.39 MB
  float* g1            = (float*)(ws + 33652736);             // 33.6 MB
  unsigned short* h1bf = (unsigned short*)(ws + 67207168);    // 0.5 MB
  float* g2            = (float*)(ws + 67731456);             // 33.6 MB
  unsigned short* h2bf = (unsigned short*)(ws + 101285888);   // 0.5 MB
  float* g3            = (float*)(ws + 101810176);            // 33.6 MB
  unsigned* ctr        = (unsigned*)(ws + 135364608);         // 64 B

  hipMemsetAsync(ctr, 0, 64, stream);            // barrier counter = 0
  fused_kernel<<<512, 256, 0, stream>>>(
      X, Qw, Qb, Kw, Kb, Vw, Vb, W1, b1, W2, b2, W3, b3, (float*)d_out,
      wT, q_ws, k_ws, vT_ws, r_ws, g1, h1bf, g2, h2bf, g3, ctr);
}

// Round 4
// 714.821 us; speedup vs baseline: 2.6957x; 2.6957x over previous
//
#include <hip/hip_runtime.h>

// ---------------------------------------------------------------------------
// TimeSeriesTransformer, 5-dispatch pipeline:
//  memset(cnt) | proj (w-transpose folded) | attn | gemm+tailreduce x3
// GEMM: K-split slabs + tail-block fused reduce/bias/sigmoid (one acq_rel
// atomic per block, no spinning). Waves split M x N (2x2) to halve LDS reads.
// ---------------------------------------------------------------------------

#define DI __device__ __forceinline__
#define AS1 __attribute__((address_space(1)))
#define AS3 __attribute__((address_space(3)))

typedef __attribute__((ext_vector_type(4))) float f32x4;
typedef __attribute__((ext_vector_type(8))) short bf16x8;

DI unsigned short f2bf(float f) {      // fp32 -> bf16, round-to-nearest-even
  unsigned int u = __float_as_uint(f);
  u += 0x7fffu + ((u >> 16) & 1u);
  return (unsigned short)(u >> 16);
}

// ---- proj: q,k row-major bf16 [B*T][128]; v transposed [B][128][256] -------
// Weight bf16 conversion folded in: B-frags built from global fp32 (L2-hot).
__global__ __launch_bounds__(256) void proj_kernel(
    const float* __restrict__ X,
    const float* __restrict__ Qw, const float* __restrict__ Qb,
    const float* __restrict__ Kw, const float* __restrict__ Kb,
    const float* __restrict__ Vw, const float* __restrict__ Vb,
    unsigned short* __restrict__ q_ws, unsigned short* __restrict__ k_ws,
    unsigned short* __restrict__ vT_ws) {
  __shared__ __align__(16) unsigned short vtile[64 * 128];   // 16 KB
  int wv = threadIdx.x >> 6, lane = threadIdx.x & 63;
  int quad = lane >> 4, l15 = lane & 15;
  int R0blk = blockIdx.x * 64;
  int R0 = R0blk + wv * 16;

  bf16x8 af[4];                          // A-frags of X, shared by q/k/v
  const float* xbase = X + (size_t)(R0 + l15) * 128 + quad * 8;
#pragma unroll
  for (int kc = 0; kc < 4; ++kc) {
    f32x4 x0 = *(const f32x4*)(xbase + kc * 32);
    f32x4 x1 = *(const f32x4*)(xbase + kc * 32 + 4);
    bf16x8 a;
#pragma unroll
    for (int j = 0; j < 4; ++j) { a[j] = (short)f2bf(x0[j]); a[4 + j] = (short)f2bf(x1[j]); }
    af[kc] = a;
  }

#pragma unroll
  for (int p = 0; p < 3; ++p) {
    const float* W = (p == 0) ? Qw : (p == 1) ? Kw : Vw;
    const float* bias = (p == 0) ? Qb : (p == 1) ? Kb : Vb;
#pragma unroll
    for (int nt = 0; nt < 8; ++nt) {
      int no = nt * 16 + l15;
      f32x4 acc = {0.f, 0.f, 0.f, 0.f};
#pragma unroll
      for (int kc = 0; kc < 4; ++kc) {
        bf16x8 b;                        // B[k=ni][n=no] = W[ni][no]
#pragma unroll
        for (int j = 0; j < 8; ++j)
          b[j] = (short)f2bf(W[(size_t)(kc * 32 + quad * 8 + j) * 128 + no]);
        acc = __builtin_amdgcn_mfma_f32_16x16x32_bf16(af[kc], b, acc, 0, 0, 0);
      }
      float bv = bias[no];
#pragma unroll
      for (int r4 = 0; r4 < 4; ++r4) {   // C/D: col=l15, row=quad*4+r4
        unsigned short val = f2bf(acc[r4] + bv);
        int rowLoc = wv * 16 + quad * 4 + r4;
        int row = R0blk + rowLoc;
        if (p == 0)      q_ws[(size_t)row * 128 + no] = val;
        else if (p == 1) k_ws[(size_t)row * 128 + no] = val;
        else             vtile[rowLoc * 128 + no] = val;
      }
    }
  }
  __syncthreads();
  {  // vT[b][no][t]: 32 shorts/thread as 4 x 16 B stores
    int no = threadIdx.x >> 1;
    int th = (threadIdx.x & 1) * 32;
    int bb2 = R0blk >> 8;
    int tBase = (R0blk & 255) + th;
    unsigned short* dst = vT_ws + ((size_t)bb2 * 128 + no) * 256 + tBase;
#pragma unroll
    for (int g = 0; g < 4; ++g) {
      bf16x8 v8;
#pragma unroll
      for (int i = 0; i < 8; ++i) v8[i] = (short)vtile[(th + g * 8 + i) * 128 + no];
      *(bf16x8*)(dst + g * 8) = v8;
    }
  }
}

// ---- attention: per block 64 t-rows of one batch; wave = 16-row tile -------
__global__ __launch_bounds__(256) void attn_kernel(
    const unsigned short* __restrict__ q_ws, const unsigned short* __restrict__ k_ws,
    const unsigned short* __restrict__ vT_ws, unsigned short* __restrict__ r_ws) {
  __shared__ __align__(16) unsigned short p_lds[4][16 * 264];
  int wv = threadIdx.x >> 6, lane = threadIdx.x & 63;
  int quad = lane >> 4, l15 = lane & 15;
  int b  = blockIdx.x >> 2;
  int t0 = (blockIdx.x & 3) * 64 + wv * 16;

  bf16x8 kf[4];
  const unsigned short* kbase = k_ws + ((size_t)b * 256 + t0 + l15) * 128 + quad * 8;
#pragma unroll
  for (int kc = 0; kc < 4; ++kc) kf[kc] = *(const bf16x8*)(kbase + kc * 32);

  f32x4 sc[16];
#pragma unroll
  for (int st = 0; st < 16; ++st) {
    f32x4 acc = {0.f, 0.f, 0.f, 0.f};
    const unsigned short* qbase = q_ws + ((size_t)b * 256 + st * 16 + l15) * 128 + quad * 8;
#pragma unroll
    for (int kc = 0; kc < 4; ++kc) {
      bf16x8 qf = *(const bf16x8*)(qbase + kc * 32);
      acc = __builtin_amdgcn_mfma_f32_16x16x32_bf16(kf[kc], qf, acc, 0, 0, 0);
    }
    sc[st] = acc;
  }

  float inv[4];
#pragma unroll
  for (int r4 = 0; r4 < 4; ++r4) {
    float m = sc[0][r4];
#pragma unroll
    for (int st = 1; st < 16; ++st) m = fmaxf(m, sc[st][r4]);
#pragma unroll
    for (int d = 1; d < 16; d <<= 1) m = fmaxf(m, __shfl_xor(m, d, 64));
    float s = 0.f;
#pragma unroll
    for (int st = 0; st < 16; ++st) { float e = __expf(sc[st][r4] - m); sc[st][r4] = e; s += e; }
#pragma unroll
    for (int d = 1; d < 16; d <<= 1) s += __shfl_xor(s, d, 64);
    inv[r4] = 1.f / s;
  }

#pragma unroll
  for (int st = 0; st < 16; ++st)
#pragma unroll
    for (int r4 = 0; r4 < 4; ++r4)
      p_lds[wv][(quad * 4 + r4) * 264 + st * 16 + l15] = f2bf(sc[st][r4] * inv[r4]);
  __syncthreads();

  const unsigned short* pbase = &p_lds[wv][l15 * 264 + quad * 8];
#pragma unroll
  for (int vt = 0; vt < 8; ++vt) {
    f32x4 acc = {0.f, 0.f, 0.f, 0.f};
    const unsigned short* vbase = vT_ws + ((size_t)b * 128 + vt * 16 + l15) * 256 + quad * 8;
#pragma unroll
    for (int s8 = 0; s8 < 8; ++s8) {
      bf16x8 pf = *(const bf16x8*)(pbase + s8 * 32);
      bf16x8 vf = *(const bf16x8*)(vbase + s8 * 32);
      acc = __builtin_amdgcn_mfma_f32_16x16x32_bf16(pf, vf, acc, 0, 0, 0);
    }
#pragma unroll
    for (int r4 = 0; r4 < 4; ++r4)
      r_ws[((size_t)b * 256 + t0 + quad * 4 + r4) * 128 + vt * 16 + l15] = f2bf(acc[r4]);
  }
}

// ---- K-split GEMM + tail-fused reduce/bias/(sigmoid) -----------------------
// A bf16 [128 x lda]. B fp32 [K x ldb] staged via global_load_lds dwordx4.
// Waves split 2x2 (M-half x N-half): 32 conflicted ds_read_b32 per chunk/wave.
// Last block per bx stripe (acq_rel atomic) reduces nSlabs slabs -> out.
template <int SIG>
__global__ __launch_bounds__(256, 2) void gemm_red(
    const unsigned short* __restrict__ A, int lda,
    const float* __restrict__ B, int ldb,
    float* __restrict__ slab, int nChunks, int nSlabs,
    const float* __restrict__ bias, void* __restrict__ outp,
    unsigned* __restrict__ cnt) {
  __shared__ __align__(16) float buf[2][32 * 128];   // 2 x 16 KB chunks
  __shared__ int lastFlag;
  const int tid = threadIdx.x;
  const int wv = tid >> 6, lane = tid & 63;
  const int quad = lane >> 4, l15 = lane & 15;
  const int wm = wv & 1, wn = wv >> 1;
  const int bx = blockIdx.x, by = blockIdx.y;
  const int n0 = bx * 128;
  const size_t k0 = (size_t)by * nChunks * 32;

  f32x4 acc[4][4];
#pragma unroll
  for (int mt = 0; mt < 4; ++mt)
#pragma unroll
    for (int nt = 0; nt < 4; ++nt) acc[mt][nt] = (f32x4){0.f, 0.f, 0.f, 0.f};

  auto stage = [&](int c, int pb) {
    const float* gsrc = B + (k0 + c * 32 + wv * 8 + (lane >> 5)) * (size_t)ldb
                          + n0 + (lane & 31) * 4;
    float* ldst = &buf[pb][(wv * 8) * 128];
#pragma unroll
    for (int i = 0; i < 4; ++i) {
      __builtin_amdgcn_global_load_lds((AS1 const void*)gsrc, (AS3 void*)ldst, 16, 0, 0);
      gsrc += 2 * (size_t)ldb;
      ldst += 256;
    }
  };

  stage(0, 0);
  for (int c = 0; c < nChunks; ++c) {
    int pb = c & 1;
    __syncthreads();                         // chunk c landed
    if (c + 1 < nChunks) stage(c + 1, pb ^ 1);

    bf16x8 aF[4];
    const unsigned short* ab = A + (size_t)(wm * 64 + l15) * lda + k0 + c * 32 + quad * 8;
#pragma unroll
    for (int mt = 0; mt < 4; ++mt) aF[mt] = *(const bf16x8*)(ab + (size_t)mt * 16 * lda);
#pragma unroll
    for (int nt = 0; nt < 4; ++nt) {
      const float* bb = &buf[pb][(quad * 8) * 128 + wn * 64 + nt * 16 + l15];
      bf16x8 bF;
#pragma unroll
      for (int j = 0; j < 8; ++j) bF[j] = (short)f2bf(bb[j * 128]);
#pragma unroll
      for (int mt = 0; mt < 4; ++mt)
        acc[mt][nt] = __builtin_amdgcn_mfma_f32_16x16x32_bf16(aF[mt], bF, acc[mt][nt], 0, 0, 0);
    }
    __syncthreads();
  }

  float* sout = slab + (size_t)by * (size_t)ldb * 128;
#pragma unroll
  for (int mt = 0; mt < 4; ++mt)
#pragma unroll
    for (int nt = 0; nt < 4; ++nt)
#pragma unroll
      for (int r4 = 0; r4 < 4; ++r4)
        sout[(size_t)(wm * 64 + mt * 16 + quad * 4 + r4) * ldb
             + n0 + wn * 64 + nt * 16 + l15] = acc[mt][nt][r4];

  // ---- tail: last by-block for this bx reduces the stripe ------------------
  __threadfence();                           // release slab stores (L2 wb)
  if (tid == 0) {
    unsigned old = __hip_atomic_fetch_add(&cnt[bx], 1u, __ATOMIC_ACQ_REL,
                                          __HIP_MEMORY_SCOPE_AGENT);
    lastFlag = (old == (unsigned)(nSlabs - 1));
  }
  __syncthreads();
  if (!lastFlag) return;
  __threadfence();                           // acquire other blocks' slabs

  int colg = tid & 31;                       // 32 groups x 4 cols = 128 cols
  int rowg = tid >> 5;                       // 8 groups x 16 rows
  const float* sbase = slab + n0 + colg * 4;
  f32x4 bv = *(const f32x4*)(bias + n0 + colg * 4);
  for (int rr = 0; rr < 16; ++rr) {
    int row = rowg * 16 + rr;
    f32x4 s = {0.f, 0.f, 0.f, 0.f};
#pragma unroll 8
    for (int y = 0; y < nSlabs; ++y) {
      f32x4 v = *(const f32x4*)(sbase + ((size_t)y * 128 + row) * (size_t)ldb);
      s.x += v.x; s.y += v.y; s.z += v.z; s.w += v.w;
    }
    s.x += bv.x; s.y += bv.y; s.z += bv.z; s.w += bv.w;
    if (SIG) {
      unsigned long long pk = 0;
#pragma unroll
      for (int j = 0; j < 4; ++j) {
        float sv = (j == 0) ? s.x : (j == 1) ? s.y : (j == 2) ? s.z : s.w;
        pk |= (unsigned long long)f2bf(1.f / (1.f + __expf(-sv))) << (16 * j);
      }
      *(unsigned long long*)((unsigned short*)outp + (size_t)row * ldb + n0 + colg * 4) = pk;
    } else {
      *(f32x4*)((float*)outp + (size_t)row * ldb + n0 + colg * 4) = s;
    }
  }
}

// ---------------------------------------------------------------------------
extern "C" void kernel_launch(void* const* d_in, const int* in_sizes, int n_in,
                              void* d_out, int out_size, void* d_ws, size_t ws_size,
                              hipStream_t stream) {
  const float* X  = (const float*)d_in[0];
  const float* Qw = (const float*)d_in[1];
  const float* Qb = (const float*)d_in[2];
  const float* Kw = (const float*)d_in[3];
  const float* Kb = (const float*)d_in[4];
  const float* Vw = (const float*)d_in[5];
  const float* Vb = (const float*)d_in[6];
  const float* W1 = (const float*)d_in[7];
  const float* b1 = (const float*)d_in[8];
  const float* W2 = (const float*)d_in[9];
  const float* b2 = (const float*)d_in[10];
  const float* W3 = (const float*)d_in[11];
  const float* b3 = (const float*)d_in[12];

  char* ws = (char*)d_ws;
  unsigned short* q_ws  = (unsigned short*)(ws + 0);          // 8.39 MB
  unsigned short* k_ws  = (unsigned short*)(ws + 8388608);    // 8.39 MB
  unsigned short* vT_ws = (unsigned short*)(ws + 16777216);   // 8.39 MB
  unsigned short* r_ws  = (unsigned short*)(ws + 25165824);   // 8.39 MB
  float* g1            = (float*)(ws + 33554432);             // 32 MB
  unsigned short* h1bf = (unsigned short*)(ws + 67108864);    // 0.5 MB
  float* g2            = (float*)(ws + 67633152);             // 8 MB
  unsigned short* h2bf = (unsigned short*)(ws + 76021760);    // 0.5 MB
  float* g3            = (float*)(ws + 76546048);             // 16 MB
  unsigned* cnt        = (unsigned*)(ws + 93323264);          // 256 B

  hipMemsetAsync(cnt, 0, 256, stream);
  proj_kernel<<<512, 256, 0, stream>>>(X, Qw, Qb, Kw, Kb, Vw, Vb,
                                       q_ws, k_ws, vT_ws);
  attn_kernel<<<512, 256, 0, stream>>>(q_ws, k_ws, vT_ws, r_ws);
  // h1 = sigmoid(r @ W1 + b1): K=32768, 32-way split, tail-fused reduce
  gemm_red<1><<<dim3(16, 32), 256, 0, stream>>>(r_ws, 32768, W1, 2048,
                                                g1, 32, 32, b1, h1bf, cnt);
  // h2 = sigmoid(h1 @ W2 + b2): K=2048, 8-way split
  gemm_red<1><<<dim3(16, 8), 256, 0, stream>>>(h1bf, 2048, W2, 2048,
                                               g2, 8, 8, b2, h2bf, cnt + 16);
  // out = h2 @ W3 + b3: K=2048, 8-way split, N=4096
  gemm_red<0><<<dim3(32, 8), 256, 0, stream>>>(h2bf, 2048, W3, 4096,
                                               g3, 8, 8, b3, (float*)d_out, cnt + 32);
}